// Round 2
// baseline (149970.947 us; speedup 1.0000x reference)
//
#include <hip/hip_runtime.h>

typedef unsigned int u32;
typedef unsigned long long u64;
typedef float f32x4 __attribute__((ext_vector_type(4)));

// np-bit-exact Leaky update: m' = f32(f32(f32(0.95f*m) + cur) - reset)
// reset from PREVIOUS mem; (mem-1>0) === (mem>1) exactly in f32 (Sterbenz).
__device__ __forceinline__ float leaky(float m, float cur) {
  float r = (m > 1.0f) ? 1.0f : 0.0f;
  return __fsub_rn(__fadd_rn(__fmul_rn(0.95f, m), cur), r);
}

// ---------------------------------------------------------------------------
// Phase A: cur1 (exact FMA chain, d ascending) + layer-1 sim; emit per-step
// spike bitmasks to global in [t][kw][sample] layout (word kw covers
// k in [kw*32, kw*32+32), bit i <-> k = kw*32+i).
// Wave = 1 sample, block = 4 waves.
// ---------------------------------------------------------------------------
__global__ __launch_bounds__(256) void k_spk1(
    const float* __restrict__ x, const float* __restrict__ W1,
    const float* __restrict__ b1, u32* __restrict__ masks,
    int s0, int Sc) {
  __shared__ float w1s[8 * 1024];
  const int tid = threadIdx.x, lane = tid & 63, w = tid >> 6;
  const int sl = blockIdx.x * 4 + w;
  const size_t s = (size_t)s0 + sl;

  float c1[16];
#pragma unroll
  for (int j = 0; j < 16; ++j) c1[j] = 0.0f;
#pragma unroll 1
  for (int ch = 0; ch < 8; ++ch) {
    __syncthreads();
#pragma unroll
    for (int it = 0; it < 8; ++it) {
      int v = tid + it * 256;
      *(f32x4*)(w1s + v * 4) =
          *(const f32x4*)(W1 + (size_t)(ch * 8 + (v >> 8)) * 1024 + (v & 255) * 4);
    }
    __syncthreads();
#pragma unroll 1
    for (int dl = 0; dl < 8; ++dl) {
      float xv = x[s * 64 + ch * 8 + dl];
#pragma unroll
      for (int j = 0; j < 16; ++j)
        c1[j] = fmaf(xv, w1s[dl * 1024 + j * 64 + lane], c1[j]);
    }
  }
#pragma unroll
  for (int j = 0; j < 16; ++j) c1[j] = __fadd_rn(c1[j], b1[j * 64 + lane]);

  float m1[16];
#pragma unroll
  for (int j = 0; j < 16; ++j) m1[j] = 0.0f;

#pragma unroll 1
  for (int t = 0; t < 25; ++t) {
#pragma unroll
    for (int j = 0; j < 16; ++j) {
      m1[j] = leaky(m1[j], c1[j]);
      u64 ball = __ballot(m1[j] > 1.0f);
      if (lane == 0) {
        masks[((size_t)t * 32 + 2 * j) * Sc + sl] = (u32)ball;
        masks[((size_t)t * 32 + 2 * j + 1) * Sc + sl] = (u32)(ball >> 32);
      }
    }
  }
}

// ---------------------------------------------------------------------------
// Phase B: cur2 for 16 samples x 1 step per wave (1-wave workgroups).
// k-outer shared row stream: each W2 row loaded ONCE per wave (2x dwordx4,
// n = lane*4 + q*256, 1KB coalesced per instr), gated add per sample via
// wave-uniform scalar branch (s_and SCC + s_cbranch: 2 SALU per (g,k)).
// Accumulators are 32 NAMED f32x4 vars (no array alloca -> no scratch spill;
// round-1's a[16][2] array was SROA'd to scratch: VGPR_Count=84, 5x slowdown).
// Ascending-k f32 add chain per n is bit-identical to the BLAS fma chain
// (fma(0,w,c)=c exact, fma(1,w,c)=add with single RN rounding).
// ---------------------------------------------------------------------------
#define FOR16(M) M(0) M(1) M(2) M(3) M(4) M(5) M(6) M(7) \
                 M(8) M(9) M(10) M(11) M(12) M(13) M(14) M(15)

#define DECL_ACC(i) f32x4 aA##i = {0.f, 0.f, 0.f, 0.f}; \
                    f32x4 aB##i = {0.f, 0.f, 0.f, 0.f};
#define LOADW(i)    const u32 w##i = (u32)__builtin_amdgcn_readfirstlane(mp[i]);
#define GADDA(i)    if (w##i & mA) { aA##i += rA0; aB##i += rA1; }
#define GADDB(i)    if (w##i & mB) { aA##i += rB0; aB##i += rB1; }
#define STORE16(i)  { f32x4 o0 = aA##i + bv0; f32x4 o1 = aB##i + bv1; \
                      float* op = cur2 + ((size_t)(sl0 + i) * 25 + t) * 512 + lq; \
                      *(f32x4*)op = o0; *(f32x4*)(op + 256) = o1; }

__global__ __launch_bounds__(64, 1) void k_cur2(
    const float* __restrict__ W2, const float* __restrict__ b2,
    const u32* __restrict__ masks, float* __restrict__ cur2, int Sc) {
  const int lane = threadIdx.x & 63;
  const int task = blockIdx.x;            // (grp, t), grid = (Sc/16)*25
  const int grp = task / 25, t = task - grp * 25;
  const int sl0 = grp * 16;
  const int lq = lane * 4;

  FOR16(DECL_ACC)

  const float* wp = W2 + lq;              // row k quad0 at wp+k*512, quad1 +256
  f32x4 rA0 = *(const f32x4*)(wp);
  f32x4 rA1 = *(const f32x4*)(wp + 256);
  f32x4 rB0, rB1;

#pragma unroll 1
  for (int kw = 0; kw < 32; ++kw) {
    const u32* mp = masks + ((size_t)t * 32 + kw) * Sc + sl0;
    FOR16(LOADW)
#pragma unroll 1
    for (int k2 = 0; k2 < 32; k2 += 2) {
      const int k = kw * 32 + k2;
      const u32 mA = 1u << k2;            // one s_lshl, shared by 16 tests
      const u32 mB = 2u << k2;
      const float* pB = wp + (size_t)(k + 1) * 512;
      rB0 = *(const f32x4*)(pB);
      rB1 = *(const f32x4*)(pB + 256);
      FOR16(GADDA)                        // row k applied before row k+1
      const int kn = (k + 2 < 1024) ? k + 2 : 1023;  // harmless clamp at tail
      const float* pA = wp + (size_t)kn * 512;
      rA0 = *(const f32x4*)(pA);
      rA1 = *(const f32x4*)(pA + 256);
      FOR16(GADDB)
    }
  }

  const f32x4 bv0 = *(const f32x4*)(b2 + lq);
  const f32x4 bv1 = *(const f32x4*)(b2 + 256 + lq);
  FOR16(STORE16)
}

// ---------------------------------------------------------------------------
// Phase C: layers 2-3 recurrence off stored cur2 (exact f32 round-trip).
// Wave = 1 sample; n = j*64+lane mapping so ballots give n-ordered words;
// lane-0 ascending-n ffs chain with 1-deep LDS-load pipeline.
// Mean+sigmoid in f64.
// ---------------------------------------------------------------------------
__global__ __launch_bounds__(256) void k_tail(
    const float* __restrict__ cur2, const float* __restrict__ W3,
    const float* __restrict__ b3, float* __restrict__ out, int s0, int Sc) {
  __shared__ float w3s[512];
  const int tid = threadIdx.x, lane = tid & 63, w = tid >> 6;
  const int sl = blockIdx.x * 4 + w;
  for (int i = tid; i < 512; i += 256) w3s[i] = W3[i];
  __syncthreads();

  float m2[8];
#pragma unroll
  for (int j = 0; j < 8; ++j) m2[j] = 0.0f;
  float m3 = 0.0f;
  double s3 = 0.0;
  const float b3v = b3[0];
  const float* cp = cur2 + (size_t)sl * 25 * 512;

#pragma unroll 1
  for (int t = 0; t < 25; ++t) {
    u64 s2b[8];
#pragma unroll
    for (int j = 0; j < 8; ++j) {
      float cur = cp[t * 512 + j * 64 + lane];
      m2[j] = leaky(m2[j], cur);
      s2b[j] = __ballot(m2[j] > 1.0f);
    }
    if (lane == 0) {
      float c3 = 0.0f;
#pragma unroll 1
      for (int j = 0; j < 8; ++j) {
        u64 mm = s2b[j];
        const int nb = j * 64;
        if (mm) {
          int nn = __ffsll(mm) - 1;
          mm &= mm - 1;
          float wv = w3s[nb + nn];
          while (mm) {
            int n2 = __ffsll(mm) - 1;
            mm &= mm - 1;
            float wn = w3s[nb + n2];   // next load issued before dependent add
            c3 = __fadd_rn(c3, wv);
            wv = wn;
          }
          c3 = __fadd_rn(c3, wv);
        }
      }
      c3 = __fadd_rn(c3, b3v);
      m3 = leaky(m3, c3);
      s3 += (double)m3;
    }
  }
  if (lane == 0) {
    double z = s3 / 25.0;
    out[s0 + sl] = (float)(1.0 / (1.0 + exp(-z)));
  }
}

// ---------------------------------------------------------------------------
// Fallback: original verified single-kernel path (used if workspace too small)
// ---------------------------------------------------------------------------
__global__ __launch_bounds__(256) void k_snn(
    const float* __restrict__ x, const float* __restrict__ W1,
    const float* __restrict__ b1, const float* __restrict__ W2,
    const float* __restrict__ b2, const float* __restrict__ W3,
    const float* __restrict__ b3, float* __restrict__ out) {
  __shared__ float w1s[8 * 1024];
  __shared__ float w3s[512];
  __shared__ u32 spkm[4][32];
  const int tid = threadIdx.x, lane = tid & 63, w = tid >> 6;
  const size_t s = (size_t)blockIdx.x * 4 + w;

  for (int i = tid; i < 512; i += 256) w3s[i] = W3[i];

  float c1[16];
#pragma unroll
  for (int j = 0; j < 16; ++j) c1[j] = 0.0f;
#pragma unroll 1
  for (int ch = 0; ch < 8; ++ch) {
    __syncthreads();
#pragma unroll
    for (int it = 0; it < 8; ++it) {
      int v = tid + it * 256;
      *(f32x4*)(w1s + v * 4) =
          *(const f32x4*)(W1 + (size_t)(ch * 8 + (v >> 8)) * 1024 + (v & 255) * 4);
    }
    __syncthreads();
#pragma unroll 1
    for (int dl = 0; dl < 8; ++dl) {
      float xv = x[s * 64 + ch * 8 + dl];
#pragma unroll
      for (int j = 0; j < 16; ++j)
        c1[j] = fmaf(xv, w1s[dl * 1024 + j * 64 + lane], c1[j]);
    }
  }
#pragma unroll
  for (int j = 0; j < 16; ++j) c1[j] = __fadd_rn(c1[j], b1[j * 64 + lane]);

  float m1[16];
#pragma unroll
  for (int j = 0; j < 16; ++j) m1[j] = 0.0f;
  float m2[8];
#pragma unroll
  for (int j = 0; j < 8; ++j) m2[j] = 0.0f;
  float b2l[8];
#pragma unroll
  for (int j = 0; j < 8; ++j) b2l[j] = b2[j * 64 + lane];
  const float b3v = b3[0];
  float m3 = 0.0f;
  double s3 = 0.0;

#pragma unroll 1
  for (int t = 0; t < 25; ++t) {
#pragma unroll
    for (int j = 0; j < 16; ++j) {
      m1[j] = leaky(m1[j], c1[j]);
      u64 ball = __ballot(m1[j] > 1.0f);
      if (lane == 0) {
        spkm[w][2 * j]     = (u32)ball;
        spkm[w][2 * j + 1] = (u32)(ball >> 32);
      }
    }
    __syncthreads();

    float c2[8];
#pragma unroll
    for (int j = 0; j < 8; ++j) c2[j] = 0.0f;
#pragma unroll 1
    for (int kw = 0; kw < 32; ++kw) {
      u32 mask = spkm[w][kw];
      int kbase = kw * 32;
      while (mask) {
        int kk = __ffs(mask) - 1;
        mask &= mask - 1;
        const float* wr = W2 + (size_t)(kbase + kk) * 512;
#pragma unroll
        for (int j = 0; j < 8; ++j)
          c2[j] = __fadd_rn(c2[j], wr[j * 64 + lane]);
      }
    }
    u64 s2b[8];
#pragma unroll
    for (int j = 0; j < 8; ++j) {
      float cur = __fadd_rn(c2[j], b2l[j]);
      m2[j] = leaky(m2[j], cur);
      s2b[j] = __ballot(m2[j] > 1.0f);
    }

    if (lane == 0) {
      float c3 = 0.0f;
#pragma unroll 1
      for (int j = 0; j < 8; ++j) {
        u64 mm = s2b[j];
        int nb = j * 64;
        while (mm) {
          int nn = __ffsll(mm) - 1;
          mm &= mm - 1;
          c3 = __fadd_rn(c3, w3s[nb + nn]);
        }
      }
      c3 = __fadd_rn(c3, b3v);
      m3 = leaky(m3, c3);
      s3 += (double)m3;
    }
    __syncthreads();
  }

  if (lane == 0) {
    double z = s3 / 25.0;
    out[s] = (float)(1.0 / (1.0 + exp(-z)));
  }
}

extern "C" void kernel_launch(void* const* d_in, const int* in_sizes, int n_in,
                              void* d_out, int out_size, void* d_ws, size_t ws_size,
                              hipStream_t stream) {
  const float* x  = (const float*)d_in[0];
  const float* W1 = (const float*)d_in[1];
  const float* b1 = (const float*)d_in[2];
  const float* W2 = (const float*)d_in[3];
  const float* b2 = (const float*)d_in[4];
  const float* W3 = (const float*)d_in[5];
  const float* b3 = (const float*)d_in[6];
  float* out = (float*)d_out;

  // Per-sample workspace: masks 25*32*4 = 3200 B, cur2 25*512*4 = 51200 B.
  const long long per_sample = 54400;
  long long smax = (d_ws != nullptr) ? (long long)(ws_size / per_sample) : 0;
  long long scap = smax > 65536 ? 65536 : smax;
  int S = (int)(scap & ~63LL);

  if (S >= 256) {
    u32* masks = (u32*)d_ws;
    float* cur2 = (float*)((char*)d_ws + (size_t)S * 3200);
    for (int s0 = 0; s0 < 65536; s0 += S) {
      int Sc = (65536 - s0 < S) ? (65536 - s0) : S;
      hipLaunchKernelGGL(k_spk1, dim3(Sc / 4), dim3(256), 0, stream,
                         x, W1, b1, masks, s0, Sc);
      hipLaunchKernelGGL(k_cur2, dim3((Sc / 16) * 25), dim3(64), 0, stream,
                         W2, b2, masks, cur2, Sc);
      hipLaunchKernelGGL(k_tail, dim3(Sc / 4), dim3(256), 0, stream,
                         cur2, W3, b3, out, s0, Sc);
    }
  } else {
    hipLaunchKernelGGL(k_snn, dim3(16384), dim3(256), 0, stream,
                       x, W1, b1, W2, b2, W3, b3, out);
  }
}

// Round 5
// 25385.950 us; speedup vs baseline: 5.9076x; 5.9076x over previous
//
#include <hip/hip_runtime.h>

typedef unsigned int u32;
typedef unsigned long long u64;
typedef float f32x4 __attribute__((ext_vector_type(4)));

// np-bit-exact Leaky update: m' = f32(f32(f32(0.95f*m) + cur) - reset)
// reset from PREVIOUS mem; (mem-1>0) === (mem>1) exactly in f32 (Sterbenz).
__device__ __forceinline__ float leaky(float m, float cur) {
  float r = (m > 1.0f) ? 1.0f : 0.0f;
  return __fsub_rn(__fadd_rn(__fmul_rn(0.95f, m), cur), r);
}

// ---------------------------------------------------------------------------
// Phase A: cur1 (exact FMA chain, d ascending) + layer-1 sim; emit per-step
// spike bitmasks to global in [t][kw][sample] layout (word kw covers
// k in [kw*32, kw*32+32), bit i <-> k = kw*32+i).
// Wave = 1 sample, block = 4 waves.   (unchanged — verified round 1/2)
// ---------------------------------------------------------------------------
__global__ __launch_bounds__(256) void k_spk1(
    const float* __restrict__ x, const float* __restrict__ W1,
    const float* __restrict__ b1, u32* __restrict__ masks,
    int s0, int Sc) {
  __shared__ float w1s[8 * 1024];
  const int tid = threadIdx.x, lane = tid & 63, w = tid >> 6;
  const int sl = blockIdx.x * 4 + w;
  const size_t s = (size_t)s0 + sl;

  float c1[16];
#pragma unroll
  for (int j = 0; j < 16; ++j) c1[j] = 0.0f;
#pragma unroll 1
  for (int ch = 0; ch < 8; ++ch) {
    __syncthreads();
#pragma unroll
    for (int it = 0; it < 8; ++it) {
      int v = tid + it * 256;
      *(f32x4*)(w1s + v * 4) =
          *(const f32x4*)(W1 + (size_t)(ch * 8 + (v >> 8)) * 1024 + (v & 255) * 4);
    }
    __syncthreads();
#pragma unroll 1
    for (int dl = 0; dl < 8; ++dl) {
      float xv = x[s * 64 + ch * 8 + dl];
#pragma unroll
      for (int j = 0; j < 16; ++j)
        c1[j] = fmaf(xv, w1s[dl * 1024 + j * 64 + lane], c1[j]);
    }
  }
#pragma unroll
  for (int j = 0; j < 16; ++j) c1[j] = __fadd_rn(c1[j], b1[j * 64 + lane]);

  float m1[16];
#pragma unroll
  for (int j = 0; j < 16; ++j) m1[j] = 0.0f;

#pragma unroll 1
  for (int t = 0; t < 25; ++t) {
#pragma unroll
    for (int j = 0; j < 16; ++j) {
      m1[j] = leaky(m1[j], c1[j]);
      u64 ball = __ballot(m1[j] > 1.0f);
      if (lane == 0) {
        masks[((size_t)t * 32 + 2 * j) * Sc + sl] = (u32)ball;
        masks[((size_t)t * 32 + 2 * j + 1) * Sc + sl] = (u32)(ball >> 32);
      }
    }
  }
}

// ---------------------------------------------------------------------------
// Phase B: cur2 for 8 samples x 1 step per wave (4 waves/block, wave=task).
// k-outer shared row stream: each W2 row loaded ONCE per wave (2x dwordx4,
// n = lane*4 + q*256, 1KB coalesced per instr).
// BRANCHLESS gating: g = (mask_bit ? 1.0f : 0.0f) is a wave-uniform scalar
// select (s_and + s_cselect, no CFG); acc[e] = fmaf(g, row[e], acc[e]) is
// the literal BLAS chain: fma(1,w,c)=RN add, fma(0,w,c)=c exactly (acc is
// never -0: starts +0, RN cancellation yields +0).  k ascending.
// G=8 (not 16) + plain fmaf (no __builtin_elementwise_fma) + 256-thr blocks:
// risk-reduction after two container failures on the heavier variant.
// ---------------------------------------------------------------------------
#define FOR8(M) M(0) M(1) M(2) M(3) M(4) M(5) M(6) M(7)

#define DECL_ACC(i) f32x4 aA##i = {0.f, 0.f, 0.f, 0.f}; \
                    f32x4 aB##i = {0.f, 0.f, 0.f, 0.f};
#define LOADW(i)    const u32 w##i = (u32)__builtin_amdgcn_readfirstlane((int)mp[i]);
#define FMA4(d, g, r) d[0] = fmaf(g, r[0], d[0]); d[1] = fmaf(g, r[1], d[1]); \
                      d[2] = fmaf(g, r[2], d[2]); d[3] = fmaf(g, r[3], d[3]);
#define GFMA_A(i)   { const float g = (w##i & mA) ? 1.0f : 0.0f; \
                      FMA4(aA##i, g, rA0) FMA4(aB##i, g, rA1) }
#define GFMA_B(i)   { const float g = (w##i & mB) ? 1.0f : 0.0f; \
                      FMA4(aA##i, g, rB0) FMA4(aB##i, g, rB1) }
#define STORE8(i)   { f32x4 o0 = aA##i + bv0; f32x4 o1 = aB##i + bv1; \
                      float* op = cur2 + ((size_t)(sl0 + i) * 25 + t) * 512 + lq; \
                      *(f32x4*)op = o0; *(f32x4*)(op + 256) = o1; }

__global__ __launch_bounds__(256) void k_cur2(
    const float* __restrict__ W2, const float* __restrict__ b2,
    const u32* __restrict__ masks, float* __restrict__ cur2, int Sc) {
  const int tid = threadIdx.x, lane = tid & 63, w = tid >> 6;
  const int task = blockIdx.x * 4 + w;    // grid = (Sc/8)*25/4 blocks
  const int grp = task / 25, t = task - grp * 25;
  const int sl0 = grp * 8;
  const int lq = lane * 4;

  FOR8(DECL_ACC)

  const float* wp = W2 + lq;              // row k quad0 at wp+k*512, quad1 +256
  f32x4 rA0 = *(const f32x4*)(wp);
  f32x4 rA1 = *(const f32x4*)(wp + 256);
  f32x4 rB0, rB1;

#pragma unroll 1
  for (int kw = 0; kw < 32; ++kw) {
    const u32* mp = masks + ((size_t)t * 32 + kw) * Sc + sl0;
    FOR8(LOADW)
#pragma unroll 1
    for (int k2 = 0; k2 < 32; k2 += 2) {
      const int k = kw * 32 + k2;
      const u32 mA = 1u << k2;            // one s_lshl, shared by 8 gates
      const u32 mB = 2u << k2;
      const float* pB = wp + (size_t)(k + 1) * 512;   // prefetch row k+1
      rB0 = *(const f32x4*)(pB);
      rB1 = *(const f32x4*)(pB + 256);
      FOR8(GFMA_A)                        // row k applied before row k+1
      const int kn = (k + 2 < 1024) ? k + 2 : 1023;   // harmless clamp at tail
      const float* pA = wp + (size_t)kn * 512;        // prefetch row k+2
      rA0 = *(const f32x4*)(pA);
      rA1 = *(const f32x4*)(pA + 256);
      FOR8(GFMA_B)
    }
  }

  const f32x4 bv0 = *(const f32x4*)(b2 + lq);
  const f32x4 bv1 = *(const f32x4*)(b2 + 256 + lq);
  FOR8(STORE8)
}

// ---------------------------------------------------------------------------
// Phase C: layers 2-3 recurrence off stored cur2 (exact f32 round-trip).
// Wave = 1 sample; n = j*64+lane mapping so ballots give n-ordered words;
// lane-0 ascending-n ffs chain with 1-deep LDS-load pipeline.
// Mean+sigmoid in f64.   (unchanged — verified round 1/2)
// ---------------------------------------------------------------------------
__global__ __launch_bounds__(256) void k_tail(
    const float* __restrict__ cur2, const float* __restrict__ W3,
    const float* __restrict__ b3, float* __restrict__ out, int s0, int Sc) {
  __shared__ float w3s[512];
  const int tid = threadIdx.x, lane = tid & 63, w = tid >> 6;
  const int sl = blockIdx.x * 4 + w;
  for (int i = tid; i < 512; i += 256) w3s[i] = W3[i];
  __syncthreads();

  float m2[8];
#pragma unroll
  for (int j = 0; j < 8; ++j) m2[j] = 0.0f;
  float m3 = 0.0f;
  double s3 = 0.0;
  const float b3v = b3[0];
  const float* cp = cur2 + (size_t)sl * 25 * 512;

#pragma unroll 1
  for (int t = 0; t < 25; ++t) {
    u64 s2b[8];
#pragma unroll
    for (int j = 0; j < 8; ++j) {
      float cur = cp[t * 512 + j * 64 + lane];
      m2[j] = leaky(m2[j], cur);
      s2b[j] = __ballot(m2[j] > 1.0f);
    }
    if (lane == 0) {
      float c3 = 0.0f;
#pragma unroll 1
      for (int j = 0; j < 8; ++j) {
        u64 mm = s2b[j];
        const int nb = j * 64;
        if (mm) {
          int nn = __ffsll(mm) - 1;
          mm &= mm - 1;
          float wv = w3s[nb + nn];
          while (mm) {
            int n2 = __ffsll(mm) - 1;
            mm &= mm - 1;
            float wn = w3s[nb + n2];   // next load issued before dependent add
            c3 = __fadd_rn(c3, wv);
            wv = wn;
          }
          c3 = __fadd_rn(c3, wv);
        }
      }
      c3 = __fadd_rn(c3, b3v);
      m3 = leaky(m3, c3);
      s3 += (double)m3;
    }
  }
  if (lane == 0) {
    double z = s3 / 25.0;
    out[s0 + sl] = (float)(1.0 / (1.0 + exp(-z)));
  }
}

// ---------------------------------------------------------------------------
// Fallback: original verified single-kernel path (used if workspace too small)
// ---------------------------------------------------------------------------
__global__ __launch_bounds__(256) void k_snn(
    const float* __restrict__ x, const float* __restrict__ W1,
    const float* __restrict__ b1, const float* __restrict__ W2,
    const float* __restrict__ b2, const float* __restrict__ W3,
    const float* __restrict__ b3, float* __restrict__ out) {
  __shared__ float w1s[8 * 1024];
  __shared__ float w3s[512];
  __shared__ u32 spkm[4][32];
  const int tid = threadIdx.x, lane = tid & 63, w = tid >> 6;
  const size_t s = (size_t)blockIdx.x * 4 + w;

  for (int i = tid; i < 512; i += 256) w3s[i] = W3[i];

  float c1[16];
#pragma unroll
  for (int j = 0; j < 16; ++j) c1[j] = 0.0f;
#pragma unroll 1
  for (int ch = 0; ch < 8; ++ch) {
    __syncthreads();
#pragma unroll
    for (int it = 0; it < 8; ++it) {
      int v = tid + it * 256;
      *(f32x4*)(w1s + v * 4) =
          *(const f32x4*)(W1 + (size_t)(ch * 8 + (v >> 8)) * 1024 + (v & 255) * 4);
    }
    __syncthreads();
#pragma unroll 1
    for (int dl = 0; dl < 8; ++dl) {
      float xv = x[s * 64 + ch * 8 + dl];
#pragma unroll
      for (int j = 0; j < 16; ++j)
        c1[j] = fmaf(xv, w1s[dl * 1024 + j * 64 + lane], c1[j]);
    }
  }
#pragma unroll
  for (int j = 0; j < 16; ++j) c1[j] = __fadd_rn(c1[j], b1[j * 64 + lane]);

  float m1[16];
#pragma unroll
  for (int j = 0; j < 16; ++j) m1[j] = 0.0f;
  float m2[8];
#pragma unroll
  for (int j = 0; j < 8; ++j) m2[j] = 0.0f;
  float b2l[8];
#pragma unroll
  for (int j = 0; j < 8; ++j) b2l[j] = b2[j * 64 + lane];
  const float b3v = b3[0];
  float m3 = 0.0f;
  double s3 = 0.0;

#pragma unroll 1
  for (int t = 0; t < 25; ++t) {
#pragma unroll
    for (int j = 0; j < 16; ++j) {
      m1[j] = leaky(m1[j], c1[j]);
      u64 ball = __ballot(m1[j] > 1.0f);
      if (lane == 0) {
        spkm[w][2 * j]     = (u32)ball;
        spkm[w][2 * j + 1] = (u32)(ball >> 32);
      }
    }
    __syncthreads();

    float c2[8];
#pragma unroll
    for (int j = 0; j < 8; ++j) c2[j] = 0.0f;
#pragma unroll 1
    for (int kw = 0; kw < 32; ++kw) {
      u32 mask = spkm[w][kw];
      int kbase = kw * 32;
      while (mask) {
        int kk = __ffs(mask) - 1;
        mask &= mask - 1;
        const float* wr = W2 + (size_t)(kbase + kk) * 512;
#pragma unroll
        for (int j = 0; j < 8; ++j)
          c2[j] = __fadd_rn(c2[j], wr[j * 64 + lane]);
      }
    }
    u64 s2b[8];
#pragma unroll
    for (int j = 0; j < 8; ++j) {
      float cur = __fadd_rn(c2[j], b2l[j]);
      m2[j] = leaky(m2[j], cur);
      s2b[j] = __ballot(m2[j] > 1.0f);
    }

    if (lane == 0) {
      float c3 = 0.0f;
#pragma unroll 1
      for (int j = 0; j < 8; ++j) {
        u64 mm = s2b[j];
        int nb = j * 64;
        while (mm) {
          int nn = __ffsll(mm) - 1;
          mm &= mm - 1;
          c3 = __fadd_rn(c3, w3s[nb + nn]);
        }
      }
      c3 = __fadd_rn(c3, b3v);
      m3 = leaky(m3, c3);
      s3 += (double)m3;
    }
    __syncthreads();
  }

  if (lane == 0) {
    double z = s3 / 25.0;
    out[s] = (float)(1.0 / (1.0 + exp(-z)));
  }
}

extern "C" void kernel_launch(void* const* d_in, const int* in_sizes, int n_in,
                              void* d_out, int out_size, void* d_ws, size_t ws_size,
                              hipStream_t stream) {
  const float* x  = (const float*)d_in[0];
  const float* W1 = (const float*)d_in[1];
  const float* b1 = (const float*)d_in[2];
  const float* W2 = (const float*)d_in[3];
  const float* b2 = (const float*)d_in[4];
  const float* W3 = (const float*)d_in[5];
  const float* b3 = (const float*)d_in[6];
  float* out = (float*)d_out;

  // Per-sample workspace: masks 25*32*4 = 3200 B, cur2 25*512*4 = 51200 B.
  const long long per_sample = 54400;
  long long smax = (d_ws != nullptr) ? (long long)(ws_size / per_sample) : 0;
  long long scap = smax > 65536 ? 65536 : smax;
  int S = (int)(scap & ~63LL);

  if (S >= 256) {
    u32* masks = (u32*)d_ws;
    float* cur2 = (float*)((char*)d_ws + (size_t)S * 3200);
    for (int s0 = 0; s0 < 65536; s0 += S) {
      int Sc = (65536 - s0 < S) ? (65536 - s0) : S;
      hipLaunchKernelGGL(k_spk1, dim3(Sc / 4), dim3(256), 0, stream,
                         x, W1, b1, masks, s0, Sc);
      hipLaunchKernelGGL(k_cur2, dim3(((Sc / 8) * 25) / 4), dim3(256), 0, stream,
                         W2, b2, masks, cur2, Sc);
      hipLaunchKernelGGL(k_tail, dim3(Sc / 4), dim3(256), 0, stream,
                         cur2, W3, b3, out, s0, Sc);
    }
  } else {
    hipLaunchKernelGGL(k_snn, dim3(16384), dim3(256), 0, stream,
                       x, W1, b1, W2, b2, W3, b3, out);
  }
}